// Round 20
// baseline (86.320 us; speedup 1.0000x reference)
//
#include <hip/hip_runtime.h>

#define N_NODES 100000
#define N_EDGES 1600000
#define F 64
#define NPB 128                              // nodes per bucket (dst>>7)
#define NB ((N_NODES + NPB - 1) / NPB)       // 782 buckets
#define CAP 2432                             // bucket capacity (mean 2048, +8.5 sigma)
#define BLK_E 8192                           // edges per split block (= segment size)
#define NSPLIT ((N_EDGES + BLK_E - 1) / BLK_E)   // 196
#define EPT (BLK_E / 1024)                   // 8 edges per split thread (1024 thr)
#define GEMM_ROWS 256                        // rows per gemm block (16 waves)
#define NGEMM ((N_NODES + GEMM_ROWS - 1) / GEMM_ROWS)  // 391

typedef unsigned short ushort_t;
typedef unsigned int uint_t;
using bf16x8 = __attribute__((ext_vector_type(8))) short;
using f32x4  = __attribute__((ext_vector_type(4))) float;

// round-to-nearest-even float -> bf16 bits
__device__ __forceinline__ ushort_t f2bf(float x) {
    uint_t u = __float_as_uint(x);
    u += 0x7FFFu + ((u >> 16) & 1u);
    return (ushort_t)(u >> 16);
}
__device__ __forceinline__ float bflo(uint_t v) {   // low bf16 of a uint
    return __uint_as_float(v << 16);
}
__device__ __forceinline__ float bfhi(uint_t v) {   // high bf16 of a uint
    return __uint_as_float(v & 0xFFFF0000u);
}

// ---- barrier-free wave scan + block scan (NW waves) ----
__device__ __forceinline__ int wave_iscan(int v) {
    const int lane = threadIdx.x & 63;
#pragma unroll
    for (int off = 1; off < 64; off <<= 1) {
        const int y = __shfl_up(v, off);
        if (lane >= off) v += y;
    }
    return v;
}
template <int NW>
__device__ __forceinline__ int block_iscan(int v, int* wtot) {
    const int t = threadIdx.x;
    const int wv = t >> 6;
    const int ws = wave_iscan(v);
    if ((t & 63) == 63) wtot[wv] = ws;
    __syncthreads();
    int base = 0;
#pragma unroll
    for (int i = 0; i < NW - 1; ++i)
        base += (i < wv) ? wtot[i] : 0;
    return base + ws;
}

// ---------------------------------------------------------------------------
// Fused kernel (1024 threads): blocks [0, NSPLIT) counting-sort their own
// 8192-edge chunk into a private segment (rank trick; EPT=8 halves the
// per-thread serial chain; 1-bin-per-thread scan). Blocks [NSPLIT, ..) do
// hn = bf16((h@W)*norm) via MFMA, 256 rows/block (4 row-quarters x 4
// col-waves). Packed record: (src << 7) | (dst & 127).
// ---------------------------------------------------------------------------
__launch_bounds__(1024)
__global__ void gemm_split_kernel(const float* __restrict__ h,
                                  const float* __restrict__ w,
                                  const float* __restrict__ norm,
                                  ushort_t* __restrict__ hn,
                                  const int* __restrict__ src,
                                  const int* __restrict__ dst,
                                  ushort_t* __restrict__ offtab,
                                  uint_t* __restrict__ seg) {
    __shared__ int hist[1024];   // bucket counts (zero-padded past NB)
    __shared__ int base[1024];   // per-bin base offsets (read-only in pass 2)
    __shared__ int wtot[16];     // wave totals for block scan
    const int t = threadIdx.x;

    if (blockIdx.x < NSPLIT) {
        // ---- split role ----
        const int e0 = blockIdx.x * BLK_E;
        const int n  = min(BLK_E, N_EDGES - e0);

        hist[t] = 0;
        __syncthreads();

        uint_t rec[EPT];
        short  bin[EPT];
        short  rnk[EPT];
#pragma unroll
        for (int j = 0; j < EPT; ++j) {
            const int idx = t + j * 1024;
            if (idx < n) {
                const int d = dst[e0 + idx];
                const int s = src[e0 + idx];
                bin[j] = (short)(d >> 7);
                rec[j] = ((uint_t)s << 7) | (uint_t)(d & 127);
                rnk[j] = (short)atomicAdd(&hist[bin[j]], 1);
            } else {
                bin[j] = -1;
            }
        }
        __syncthreads();

        // exclusive scan, 1 bin/thread (bins >= NB are zero)
        const int v = hist[t];
        const int incl = block_iscan<16>(v, wtot);
        const int run = incl - v;
        ushort_t* offrow = offtab + (size_t)blockIdx.x * (NB + 1);
        if (t < NB) {
            offrow[t] = (ushort_t)run;
            base[t] = run;
        } else if (t == NB) {
            offrow[NB] = (ushort_t)run;   // == n
        }
        __syncthreads();

        // pass 2: pure stores -- position = base[bin] + rank
        uint_t* myseg = seg + (size_t)blockIdx.x * BLK_E;
#pragma unroll
        for (int j = 0; j < EPT; ++j) {
            if (bin[j] >= 0)
                myseg[base[bin[j]] + rnk[j]] = rec[j];
        }
    } else {
        // ---- gemm role: MFMA, 16 waves = 4 row-quarters x 4 col-waves ----
        const int gb  = blockIdx.x - NSPLIT;
        const int wv  = t >> 6;        // 0..15
        const int l   = t & 63;
        const int lr  = l & 15;
        const int lk  = l >> 4;
        const int col = (wv & 3) * 16 + lr;
        const int r0  = gb * GEMM_ROWS + (wv >> 2) * 64;

        bf16x8 b0, b1;
#pragma unroll
        for (int j = 0; j < 8; ++j) {
            b0[j] = (short)f2bf(w[(lk * 8 + j) * F + col]);
            b1[j] = (short)f2bf(w[(32 + lk * 8 + j) * F + col]);
        }

        float4 hv[4][4];
#pragma unroll
        for (int tt = 0; tt < 4; ++tt) {
            const int r  = r0 + tt * 16 + lr;
            const int rl = min(r, N_NODES - 1);
            const float* hp = h + (size_t)rl * F + lk * 8;
            hv[tt][0] = *(const float4*)(hp);
            hv[tt][1] = *(const float4*)(hp + 4);
            hv[tt][2] = *(const float4*)(hp + 32);
            hv[tt][3] = *(const float4*)(hp + 36);
        }

        f32x4 accv[4];
#pragma unroll
        for (int tt = 0; tt < 4; ++tt) {
            bf16x8 a0, a1;
            a0[0] = (short)f2bf(hv[tt][0].x); a0[1] = (short)f2bf(hv[tt][0].y);
            a0[2] = (short)f2bf(hv[tt][0].z); a0[3] = (short)f2bf(hv[tt][0].w);
            a0[4] = (short)f2bf(hv[tt][1].x); a0[5] = (short)f2bf(hv[tt][1].y);
            a0[6] = (short)f2bf(hv[tt][1].z); a0[7] = (short)f2bf(hv[tt][1].w);
            a1[0] = (short)f2bf(hv[tt][2].x); a1[1] = (short)f2bf(hv[tt][2].y);
            a1[2] = (short)f2bf(hv[tt][2].z); a1[3] = (short)f2bf(hv[tt][2].w);
            a1[4] = (short)f2bf(hv[tt][3].x); a1[5] = (short)f2bf(hv[tt][3].y);
            a1[6] = (short)f2bf(hv[tt][3].z); a1[7] = (short)f2bf(hv[tt][3].w);

            f32x4 acc = {0.f, 0.f, 0.f, 0.f};
            acc = __builtin_amdgcn_mfma_f32_16x16x32_bf16(a0, b0, acc, 0, 0, 0);
            acc = __builtin_amdgcn_mfma_f32_16x16x32_bf16(a1, b1, acc, 0, 0, 0);
            accv[tt] = acc;
        }

#pragma unroll
        for (int tt = 0; tt < 4; ++tt) {
#pragma unroll
            for (int i2 = 0; i2 < 4; ++i2) {
                const int m = r0 + tt * 16 + lk * 4 + i2;
                if (m < N_NODES)
                    hn[(size_t)m * F + col] = f2bf(accv[tt][i2] * norm[m]);
            }
        }
    }
}

// ---------------------------------------------------------------------------
// Fused build+gather (512 thr/block, one block per bucket of 128 dst nodes):
// 16-lane-group-per-slice assembly (coalesced, count merged into copy) ->
// wave-level scans -> bucket-local per-node lists -> register-accumulating
// gather with uint4 loads (16 B/lane, 8 lanes/row, 8 edges per wave-load,
// 16-edge unroll), fused post-scale. Full 128 B rows (fetch granularity).
// ---------------------------------------------------------------------------
__launch_bounds__(512)
__global__ void gather_build_kernel(const ushort_t* __restrict__ offtab,
                                    const uint_t* __restrict__ seg,
                                    const ushort_t* __restrict__ hn,
                                    const float* __restrict__ norm,
                                    float* __restrict__ out) {
    __shared__ uint_t ebuf[CAP];        // 9.7 KB packed records
    __shared__ int    lsrc[CAP];        // 9.7 KB bucket-local edge list
    __shared__ int    cnt[NPB];
    __shared__ int    beg[NPB];
    __shared__ int    cur[NPB];
    __shared__ int    sstart[NSPLIT];
    __shared__ int    sbase[NSPLIT];
    __shared__ int    slenA[NSPLIT];
    __shared__ int    wtot[8];
    __shared__ int    tot[1];

    const int b = blockIdx.x;
    const int t = threadIdx.x;

    // ---- slice ranges (one per split block) ----
    int slen_v = 0, sstart_v = 0;
    if (t < NSPLIT) {
        const ushort_t* row = offtab + (size_t)t * (NB + 1);
        sstart_v = row[b];
        slen_v   = row[b + 1] - sstart_v;
        sstart[t] = sstart_v;
        slenA[t]  = slen_v;
    }
    if (t < NPB) cnt[t] = 0;

    const int incl = block_iscan<8>(slen_v, wtot);
    if (t < NSPLIT) sbase[t] = incl - slen_v;
    if (t == 511) tot[0] = incl;
    __syncthreads();
    const int n = min(tot[0], CAP);

    // ---- 16-lane-group per slice: coalesced copy + merged per-node count ----
    const int grp    = t >> 4;
    const int lane16 = t & 15;
    for (int s = grp; s < NSPLIT; s += 32) {
        const int len  = slenA[s];
        const int bas  = sbase[s];
        const uint_t* sp = seg + (size_t)s * BLK_E + sstart[s];
        for (int j = lane16; j < len; j += 16) {
            const int o = bas + j;
            if (o < CAP) {
                const uint_t v = sp[j];
                ebuf[o] = v;
                atomicAdd(&cnt[v & 127u], 1);
            }
        }
    }
    __syncthreads();

    // ---- scan over 128 node counts (wave-level) ----
    const int cv = (t < NPB) ? cnt[t] : 0;
    const int incl2 = block_iscan<8>(cv, wtot);
    if (t < NPB) {
        const int e = incl2 - cv;
        beg[t] = e;
        cur[t] = e;
    }
    __syncthreads();

    // ---- place into bucket-local per-node lists ----
    for (int i = t; i < n; i += 512) {
        const uint_t e = ebuf[i];
        const int p = atomicAdd(&cur[e & 127u], 1);
        lsrc[p] = (int)(e >> 7);
    }
    __syncthreads();

    // ---- gather: wave per node; slot s in [0,8) x colgroup c8 in [0,8) ----
    const int wave = t >> 6;
    const int lane = t & 63;
    const int s  = lane >> 3;   // edge slot 0..7
    const int c8 = lane & 7;    // col group: cols 8*c8 .. 8*c8+7 (16 B)

    for (int ld = wave; ld < NPB; ld += 8) {
        const int node = b * NPB + ld;
        if (node >= N_NODES) break;

        const int bg = beg[ld];
        const int en = bg + cnt[ld];

        float a0 = 0.f, a1 = 0.f, a2 = 0.f, a3 = 0.f;
        float a4 = 0.f, a5 = 0.f, a6 = 0.f, a7 = 0.f;
        int i = bg;
        for (; i + 15 < en; i += 16) {
            const int sA = lsrc[i + s];
            const int sB = lsrc[i + 8 + s];
            const uint4 vA = *(const uint4*)(hn + (size_t)sA * F + c8 * 8);
            const uint4 vB = *(const uint4*)(hn + (size_t)sB * F + c8 * 8);
            a0 += bflo(vA.x) + bflo(vB.x);
            a1 += bfhi(vA.x) + bfhi(vB.x);
            a2 += bflo(vA.y) + bflo(vB.y);
            a3 += bfhi(vA.y) + bfhi(vB.y);
            a4 += bflo(vA.z) + bflo(vB.z);
            a5 += bfhi(vA.z) + bfhi(vB.z);
            a6 += bflo(vA.w) + bflo(vB.w);
            a7 += bfhi(vA.w) + bfhi(vB.w);
        }
        for (; i + 7 < en; i += 8) {
            const int sA = lsrc[i + s];
            const uint4 vA = *(const uint4*)(hn + (size_t)sA * F + c8 * 8);
            a0 += bflo(vA.x);
            a1 += bfhi(vA.x);
            a2 += bflo(vA.y);
            a3 += bfhi(vA.y);
            a4 += bflo(vA.z);
            a5 += bfhi(vA.z);
            a6 += bflo(vA.w);
            a7 += bfhi(vA.w);
        }
        if (i < en) {
            const int e = i + s;
            if (e < en) {
                const int sv = lsrc[e];
                const uint4 v = *(const uint4*)(hn + (size_t)sv * F + c8 * 8);
                a0 += bflo(v.x);
                a1 += bfhi(v.x);
                a2 += bflo(v.y);
                a3 += bfhi(v.y);
                a4 += bflo(v.z);
                a5 += bfhi(v.z);
                a6 += bflo(v.w);
                a7 += bfhi(v.w);
            }
        }

#pragma unroll
        for (int off = 8; off < 64; off <<= 1) {
            a0 += __shfl_xor(a0, off); a1 += __shfl_xor(a1, off);
            a2 += __shfl_xor(a2, off); a3 += __shfl_xor(a3, off);
            a4 += __shfl_xor(a4, off); a5 += __shfl_xor(a5, off);
            a6 += __shfl_xor(a6, off); a7 += __shfl_xor(a7, off);
        }

        if (s == 0) {
            const float nv = norm[node];
            float4 r0v, r1v;
            r0v.x = a0 * nv; r0v.y = a1 * nv; r0v.z = a2 * nv; r0v.w = a3 * nv;
            r1v.x = a4 * nv; r1v.y = a5 * nv; r1v.z = a6 * nv; r1v.w = a7 * nv;
            float* op = out + (size_t)node * F + c8 * 8;
            *(float4*)(op)     = r0v;
            *(float4*)(op + 4) = r1v;
        }
    }
}

extern "C" void kernel_launch(void* const* d_in, const int* in_sizes, int n_in,
                              void* d_out, int out_size, void* d_ws, size_t ws_size,
                              hipStream_t stream) {
    const float* h    = (const float*)d_in[0];
    const float* w    = (const float*)d_in[1];
    const float* norm = (const float*)d_in[2];
    const int*   src  = (const int*)d_in[3];
    const int*   dst  = (const int*)d_in[4];
    float* out = (float*)d_out;

    // Workspace layout (256-aligned chunks), total ~19.6 MB:
    char* ws = (char*)d_ws;
    ushort_t* hn     = (ushort_t*)ws;                        // 12,800,000 B
    uint_t*   seg    = (uint_t*)(ws + 12800000);             //  6,422,528 B (NSPLIT*BLK_E*4)
    ushort_t* offtab = (ushort_t*)(ws + 12800000 + 6422528); //    306,936 B (NSPLIT*(NB+1)*2)

    gemm_split_kernel<<<NSPLIT + NGEMM, 1024, 0, stream>>>(
        h, w, norm, hn, src, dst, offtab, seg);

    gather_build_kernel<<<NB, 512, 0, stream>>>(offtab, seg, hn, norm, out);
}

// Round 21
// 70.348 us; speedup vs baseline: 1.2270x; 1.2270x over previous
//
#include <hip/hip_runtime.h>

#define N_NODES 100000
#define N_EDGES 1600000
#define F 64
#define NPB 128                              // nodes per bucket (dst>>7)
#define NB ((N_NODES + NPB - 1) / NPB)       // 782 buckets
#define CAP 2432                             // bucket capacity (mean 2048, +8.5 sigma)
#define BLK_E 8192                           // edges per split block (= segment size)
#define NSPLIT ((N_EDGES + BLK_E - 1) / BLK_E)   // 196
#define EPT (BLK_E / 512)                    // 16 edges per split thread (512 thr)
#define GEMM_ROWS 128                        // rows per gemm block (8 waves)
#define NGEMM ((N_NODES + GEMM_ROWS - 1) / GEMM_ROWS)  // 782

typedef unsigned short ushort_t;
typedef unsigned int uint_t;
using bf16x8 = __attribute__((ext_vector_type(8))) short;
using f32x4  = __attribute__((ext_vector_type(4))) float;

// round-to-nearest-even float -> bf16 bits
__device__ __forceinline__ ushort_t f2bf(float x) {
    uint_t u = __float_as_uint(x);
    u += 0x7FFFu + ((u >> 16) & 1u);
    return (ushort_t)(u >> 16);
}
__device__ __forceinline__ float bflo(uint_t v) {   // low bf16 of a uint
    return __uint_as_float(v << 16);
}
__device__ __forceinline__ float bfhi(uint_t v) {   // high bf16 of a uint
    return __uint_as_float(v & 0xFFFF0000u);
}

// ---- barrier-free wave scan + 2-barrier block scan (512 thr = 8 waves) ----
__device__ __forceinline__ int wave_iscan(int v) {
    const int lane = threadIdx.x & 63;
#pragma unroll
    for (int off = 1; off < 64; off <<= 1) {
        const int y = __shfl_up(v, off);
        if (lane >= off) v += y;
    }
    return v;
}
// inclusive scan across a 512-thread block; wtot = __shared__ int[8].
__device__ __forceinline__ int block_iscan(int v, int* wtot) {
    const int t = threadIdx.x;
    const int wv = t >> 6;
    const int ws = wave_iscan(v);
    if ((t & 63) == 63) wtot[wv] = ws;
    __syncthreads();
    int base = 0;
#pragma unroll
    for (int i = 0; i < 7; ++i)
        base += (i < wv) ? wtot[i] : 0;
    return base + ws;
}

// ---------------------------------------------------------------------------
// Fused kernel (512 threads): blocks [0, NSPLIT) counting-sort their own
// 8192-edge chunk into a private segment (rank trick: pass-1 histogram
// atomicAdd returns the in-bin rank; pass 2 is pure stores; wave scans).
// Blocks [NSPLIT, ..) do hn = bf16((h@W)*norm) via MFMA, 128 rows/block.
// Packed record: (src << 7) | (dst & 127).
// ---------------------------------------------------------------------------
__launch_bounds__(512)
__global__ void gemm_split_kernel(const float* __restrict__ h,
                                  const float* __restrict__ w,
                                  const float* __restrict__ norm,
                                  ushort_t* __restrict__ hn,
                                  const int* __restrict__ src,
                                  const int* __restrict__ dst,
                                  ushort_t* __restrict__ offtab,
                                  uint_t* __restrict__ seg) {
    __shared__ int hist[1024];   // bucket counts (zero-padded past NB)
    __shared__ int base[NB + 2]; // per-bin base offsets (read-only in pass 2)
    __shared__ int wtot[8];      // wave totals for block scan
    const int t = threadIdx.x;

    if (blockIdx.x < NSPLIT) {
        // ---- split role ----
        const int e0 = blockIdx.x * BLK_E;
        const int n  = min(BLK_E, N_EDGES - e0);

        for (int i = t; i < 1024; i += 512) hist[i] = 0;
        __syncthreads();

        uint_t rec[EPT];
        short  bin[EPT];
        short  rnk[EPT];
#pragma unroll
        for (int j = 0; j < EPT; ++j) {
            const int idx = t + j * 512;
            if (idx < n) {
                const int d = dst[e0 + idx];
                const int s = src[e0 + idx];
                bin[j] = (short)(d >> 7);
                rec[j] = ((uint_t)s << 7) | (uint_t)(d & 127);
                rnk[j] = (short)atomicAdd(&hist[bin[j]], 1);
            } else {
                bin[j] = -1;
            }
        }
        __syncthreads();

        // exclusive scan over 783 bins (2 bins/thread), wave-level
        const int b0i = 2 * t;
        const int v0 = hist[b0i], v1 = hist[b0i + 1];
        const int ssum = v0 + v1;
        const int incl = block_iscan(ssum, wtot);
        int run = incl - ssum;
        ushort_t* offrow = offtab + (size_t)blockIdx.x * (NB + 1);
        const int vj[2] = {v0, v1};
#pragma unroll
        for (int j = 0; j < 2; ++j) {
            const int b = b0i + j;
            if (b < NB) {
                offrow[b] = (ushort_t)run;
                base[b] = run;
            } else if (b == NB) {
                offrow[NB] = (ushort_t)run;   // == n
            }
            run += vj[j];
        }
        __syncthreads();

        // pass 2: pure stores -- position = base[bin] + rank
        uint_t* myseg = seg + (size_t)blockIdx.x * BLK_E;
#pragma unroll
        for (int j = 0; j < EPT; ++j) {
            if (bin[j] >= 0)
                myseg[base[bin[j]] + rnk[j]] = rec[j];
        }
    } else {
        // ---- gemm role: MFMA, 8 waves = 2 row-halves x 4 col-waves ----
        const int gb  = blockIdx.x - NSPLIT;
        const int wv  = t >> 6;        // 0..7
        const int l   = t & 63;
        const int lr  = l & 15;
        const int lk  = l >> 4;
        const int col = (wv & 3) * 16 + lr;
        const int r0  = gb * GEMM_ROWS + (wv >> 2) * 64;

        bf16x8 b0, b1;
#pragma unroll
        for (int j = 0; j < 8; ++j) {
            b0[j] = (short)f2bf(w[(lk * 8 + j) * F + col]);
            b1[j] = (short)f2bf(w[(32 + lk * 8 + j) * F + col]);
        }

        float4 hv[4][4];
#pragma unroll
        for (int tt = 0; tt < 4; ++tt) {
            const int r  = r0 + tt * 16 + lr;
            const int rl = min(r, N_NODES - 1);
            const float* hp = h + (size_t)rl * F + lk * 8;
            hv[tt][0] = *(const float4*)(hp);
            hv[tt][1] = *(const float4*)(hp + 4);
            hv[tt][2] = *(const float4*)(hp + 32);
            hv[tt][3] = *(const float4*)(hp + 36);
        }

        f32x4 accv[4];
#pragma unroll
        for (int tt = 0; tt < 4; ++tt) {
            bf16x8 a0, a1;
            a0[0] = (short)f2bf(hv[tt][0].x); a0[1] = (short)f2bf(hv[tt][0].y);
            a0[2] = (short)f2bf(hv[tt][0].z); a0[3] = (short)f2bf(hv[tt][0].w);
            a0[4] = (short)f2bf(hv[tt][1].x); a0[5] = (short)f2bf(hv[tt][1].y);
            a0[6] = (short)f2bf(hv[tt][1].z); a0[7] = (short)f2bf(hv[tt][1].w);
            a1[0] = (short)f2bf(hv[tt][2].x); a1[1] = (short)f2bf(hv[tt][2].y);
            a1[2] = (short)f2bf(hv[tt][2].z); a1[3] = (short)f2bf(hv[tt][2].w);
            a1[4] = (short)f2bf(hv[tt][3].x); a1[5] = (short)f2bf(hv[tt][3].y);
            a1[6] = (short)f2bf(hv[tt][3].z); a1[7] = (short)f2bf(hv[tt][3].w);

            f32x4 acc = {0.f, 0.f, 0.f, 0.f};
            acc = __builtin_amdgcn_mfma_f32_16x16x32_bf16(a0, b0, acc, 0, 0, 0);
            acc = __builtin_amdgcn_mfma_f32_16x16x32_bf16(a1, b1, acc, 0, 0, 0);
            accv[tt] = acc;
        }

#pragma unroll
        for (int tt = 0; tt < 4; ++tt) {
#pragma unroll
            for (int i2 = 0; i2 < 4; ++i2) {
                const int m = r0 + tt * 16 + lk * 4 + i2;
                if (m < N_NODES)
                    hn[(size_t)m * F + col] = f2bf(accv[tt][i2] * norm[m]);
            }
        }
    }
}

// ---------------------------------------------------------------------------
// Fused build+gather: one block (512 thr) per bucket of 128 dst nodes.
// 16-lane-group-per-slice assembly (coalesced, count merged into copy) ->
// wave-level scans -> bucket-local per-node lists -> register-accumulating
// gather (wave per node: 4 slots x 16 colgroups, uint2/lane, 16-edge
// unroll), fused post-scale. Full 128 B rows (fetch granularity).
// ---------------------------------------------------------------------------
__launch_bounds__(512)
__global__ void gather_build_kernel(const ushort_t* __restrict__ offtab,
                                    const uint_t* __restrict__ seg,
                                    const ushort_t* __restrict__ hn,
                                    const float* __restrict__ norm,
                                    float* __restrict__ out) {
    __shared__ uint_t ebuf[CAP];        // 9.7 KB packed records
    __shared__ int    lsrc[CAP];        // 9.7 KB bucket-local edge list
    __shared__ int    cnt[NPB];
    __shared__ int    beg[NPB];
    __shared__ int    cur[NPB];
    __shared__ int    sstart[NSPLIT];   // slice start within its segment
    __shared__ int    sbase[NSPLIT];    // slice exclusive prefix in ebuf
    __shared__ int    slenA[NSPLIT];    // slice length
    __shared__ int    wtot[8];
    __shared__ int    tot[1];

    const int b = blockIdx.x;
    const int t = threadIdx.x;

    // ---- slice ranges (one per split block) ----
    int slen_v = 0, sstart_v = 0;
    if (t < NSPLIT) {
        const ushort_t* row = offtab + (size_t)t * (NB + 1);
        sstart_v = row[b];
        slen_v   = row[b + 1] - sstart_v;
        sstart[t] = sstart_v;
        slenA[t]  = slen_v;
    }
    if (t < NPB) cnt[t] = 0;

    // inclusive scan of slice lengths (wave-level, 1 internal barrier)
    const int incl = block_iscan(slen_v, wtot);
    if (t < NSPLIT) sbase[t] = incl - slen_v;
    if (t == 511) tot[0] = incl;
    __syncthreads();
    const int n = min(tot[0], CAP);

    // ---- 16-lane-group per slice: coalesced copy + merged per-node count ----
    const int grp    = t >> 4;   // 0..31
    const int lane16 = t & 15;
    for (int s = grp; s < NSPLIT; s += 32) {
        const int len  = slenA[s];
        const int base = sbase[s];
        const uint_t* sp = seg + (size_t)s * BLK_E + sstart[s];
        for (int j = lane16; j < len; j += 16) {
            const int o = base + j;
            if (o < CAP) {
                const uint_t v = sp[j];
                ebuf[o] = v;
                atomicAdd(&cnt[v & 127u], 1);
            }
        }
    }
    __syncthreads();

    // ---- scan over 128 node counts (wave-level) ----
    const int cv = (t < NPB) ? cnt[t] : 0;
    const int incl2 = block_iscan(cv, wtot);
    if (t < NPB) {
        const int e = incl2 - cv;
        beg[t] = e;
        cur[t] = e;
    }
    __syncthreads();

    // ---- place into bucket-local per-node lists ----
    for (int i = t; i < n; i += 512) {
        const uint_t e = ebuf[i];
        const int p = atomicAdd(&cur[e & 127u], 1);
        lsrc[p] = (int)(e >> 7);
    }
    __syncthreads();

    // ---- gather: wave w handles local nodes w, w+8, ... ----
    const int wave = t >> 6;
    const int lane = t & 63;
    const int s = lane >> 4;   // edge slot
    const int c = lane & 15;   // col group: cols 4c..4c+3

    for (int ld = wave; ld < NPB; ld += 8) {
        const int node = b * NPB + ld;
        if (node >= N_NODES) break;

        const int bg = beg[ld];
        const int en = bg + cnt[ld];

        float a0 = 0.f, a1 = 0.f, a2 = 0.f, a3 = 0.f;
        int i = bg;
        for (; i + 15 < en; i += 16) {
            const int sA = lsrc[i + s];
            const int sB = lsrc[i + 4 + s];
            const int sC = lsrc[i + 8 + s];
            const int sD = lsrc[i + 12 + s];
            const uint2 vA = *(const uint2*)(hn + (size_t)sA * F + 4 * c);
            const uint2 vB = *(const uint2*)(hn + (size_t)sB * F + 4 * c);
            const uint2 vC = *(const uint2*)(hn + (size_t)sC * F + 4 * c);
            const uint2 vD = *(const uint2*)(hn + (size_t)sD * F + 4 * c);
            a0 += bflo(vA.x) + bflo(vB.x) + bflo(vC.x) + bflo(vD.x);
            a1 += bfhi(vA.x) + bfhi(vB.x) + bfhi(vC.x) + bfhi(vD.x);
            a2 += bflo(vA.y) + bflo(vB.y) + bflo(vC.y) + bflo(vD.y);
            a3 += bfhi(vA.y) + bfhi(vB.y) + bfhi(vC.y) + bfhi(vD.y);
        }
        for (; i + 7 < en; i += 8) {
            const int sA = lsrc[i + s];
            const int sB = lsrc[i + 4 + s];
            const uint2 vA = *(const uint2*)(hn + (size_t)sA * F + 4 * c);
            const uint2 vB = *(const uint2*)(hn + (size_t)sB * F + 4 * c);
            a0 += bflo(vA.x) + bflo(vB.x);
            a1 += bfhi(vA.x) + bfhi(vB.x);
            a2 += bflo(vA.y) + bflo(vB.y);
            a3 += bfhi(vA.y) + bfhi(vB.y);
        }
        for (; i < en; i += 4) {
            const int e = i + s;
            if (e < en) {
                const int sv = lsrc[e];
                const uint2 v = *(const uint2*)(hn + (size_t)sv * F + 4 * c);
                a0 += bflo(v.x);
                a1 += bfhi(v.x);
                a2 += bflo(v.y);
                a3 += bfhi(v.y);
            }
        }

        a0 += __shfl_xor(a0, 16); a0 += __shfl_xor(a0, 32);
        a1 += __shfl_xor(a1, 16); a1 += __shfl_xor(a1, 32);
        a2 += __shfl_xor(a2, 16); a2 += __shfl_xor(a2, 32);
        a3 += __shfl_xor(a3, 16); a3 += __shfl_xor(a3, 32);

        if (s == 0) {
            const float nv = norm[node];
            float4 r;
            r.x = a0 * nv; r.y = a1 * nv; r.z = a2 * nv; r.w = a3 * nv;
            *(float4*)(out + (size_t)node * F + 4 * c) = r;
        }
    }
}

extern "C" void kernel_launch(void* const* d_in, const int* in_sizes, int n_in,
                              void* d_out, int out_size, void* d_ws, size_t ws_size,
                              hipStream_t stream) {
    const float* h    = (const float*)d_in[0];
    const float* w    = (const float*)d_in[1];
    const float* norm = (const float*)d_in[2];
    const int*   src  = (const int*)d_in[3];
    const int*   dst  = (const int*)d_in[4];
    float* out = (float*)d_out;

    // Workspace layout (256-aligned chunks), total ~19.6 MB:
    char* ws = (char*)d_ws;
    ushort_t* hn     = (ushort_t*)ws;                        // 12,800,000 B
    uint_t*   seg    = (uint_t*)(ws + 12800000);             //  6,422,528 B (NSPLIT*BLK_E*4)
    ushort_t* offtab = (ushort_t*)(ws + 12800000 + 6422528); //    306,936 B (NSPLIT*(NB+1)*2)

    gemm_split_kernel<<<NSPLIT + NGEMM, 512, 0, stream>>>(
        h, w, norm, hn, src, dst, offtab, seg);

    gather_build_kernel<<<NB, 512, 0, stream>>>(offtab, seg, hn, norm, out);
}